// Round 7
// baseline (95.343 us; speedup 1.0000x reference)
//
#include <hip/hip_runtime.h>

// Zero-LDS FWHT-4096, y = x @ H = FWHT(x)/64.
// One row per wave (64-thread block). Load layout d = k + 4*lane + 256*q puts
// element bits {2..7} IN THE LANE INDEX, so those 6 FWHT stages are cross-lane
// shuffles (__shfl_xor masks 1,2,4,8,16,32). Bits {0,1} are inside each f32x4,
// bits {8..11} across the 16 registers. No LDS, no barriers, no fences:
// pure dataflow, occupancy VGPR-bound only.
//
// Butterfly across a lane bit: partner o = shfl_xor(v); lane with bit==0 needs
// v+o, bit==1 needs o-v  ->  r = fma(s, v, o) with s = +/-1 per lane.

constexpr int DIMV = 4096;

typedef float f32x4 __attribute__((ext_vector_type(4)));

__device__ __forceinline__ void bf4(f32x4& a, f32x4& b) {
    f32x4 t = a + b;
    b = a - b;
    a = t;
}
// FWHT on bits {0,1} (the 4 elements of one float4) — explicit temps.
__device__ __forceinline__ void fwht4_inner(f32x4& v) {
    float a = v.x, b = v.y, c = v.z, d = v.w;
    float t0 = a + b, t1 = a - b, t2 = c + d, t3 = c - d;
    v.x = t0 + t2;
    v.y = t1 + t3;
    v.z = t0 - t2;
    v.w = t1 - t3;
}

__global__ __launch_bounds__(64) void fwht4096_kernel(const float* __restrict__ x,
                                                      float* __restrict__ y) {
    const int lane = threadIdx.x;
    const long long row = blockIdx.x;

    const f32x4* xr = reinterpret_cast<const f32x4*>(x) + row * (DIMV / 4);
    f32x4*       yr = reinterpret_cast<f32x4*>(y)       + row * (DIMV / 4);

    // ---- Load 16 float4 (non-temporal): element d = 4*lane + k + 256*q
    f32x4 v[16];
#pragma unroll
    for (int q = 0; q < 16; ++q) v[q] = __builtin_nontemporal_load(&xr[lane + 64 * q]);

    const float sc = 0.015625f;  // 1/64 = 1/sqrt(4096)
#pragma unroll
    for (int q = 0; q < 16; ++q) v[q] *= sc;

    // ---- Bits {0,1}: inside each float4 (independent per q -> overlaps loads)
#pragma unroll
    for (int q = 0; q < 16; ++q) fwht4_inner(v[q]);

    // ---- Bits {2..7}: lane-index butterflies via shuffles, masks 1..32
#pragma unroll
    for (int mask = 1; mask <= 32; mask <<= 1) {
        const float s = (lane & mask) ? -1.0f : 1.0f;
#pragma unroll
        for (int q = 0; q < 16; ++q) {
            float o0 = __shfl_xor(v[q].x, mask, 64);
            float o1 = __shfl_xor(v[q].y, mask, 64);
            float o2 = __shfl_xor(v[q].z, mask, 64);
            float o3 = __shfl_xor(v[q].w, mask, 64);
            v[q].x = fmaf(s, v[q].x, o0);
            v[q].y = fmaf(s, v[q].y, o1);
            v[q].z = fmaf(s, v[q].z, o2);
            v[q].w = fmaf(s, v[q].w, o3);
        }
    }

    // ---- Bits {8..11}: across the 16 registers
#pragma unroll
    for (int st = 1; st < 16; st <<= 1) {
#pragma unroll
        for (int q = 0; q < 16; ++q) {
            if (!(q & st)) bf4(v[q], v[q | st]);
        }
    }

    // ---- Coalesced non-temporal float4 stores (same layout as load)
#pragma unroll
    for (int q = 0; q < 16; ++q) __builtin_nontemporal_store(v[q], &yr[lane + 64 * q]);
}

extern "C" void kernel_launch(void* const* d_in, const int* in_sizes, int n_in,
                              void* d_out, int out_size, void* d_ws, size_t ws_size,
                              hipStream_t stream) {
    const float* x = (const float*)d_in[0];
    float* y = (float*)d_out;
    const int rows = in_sizes[0] / DIMV;  // 16384
    dim3 grid(rows), block(64);
    hipLaunchKernelGGL(fwht4096_kernel, grid, block, 0, stream, x, y);
}

// Round 8
// 91.454 us; speedup vs baseline: 1.0425x; 1.0425x over previous
//
#include <hip/hip_runtime.h>

// Wave-private FWHT-4096, y = x @ H = FWHT(x)/64.   [R6 restoration — best]
// ONE ROW PER 64-THREAD BLOCK (1 wave). __syncthreads() in a single-wave
// workgroup compiles to a pure memory fence (no cross-wave coupling).
//
// Radix 6+6: P1 in registers (bits {0,1} inside float4 + {8..11} across the
// 16 float4s), one LDS transpose, P2 fwht64 in registers (bits {2..7}),
// write back, read in load layout, coalesced non-temporal float4 stores.
//
// LDS: 1024 float4 slots (16 KB), XOR swizzle slot' = s ^ ((s>>6)&7):
//  - stage writes / final reads (b128): 64 consecutive (permuted) slots -> minimal.
//  - P2 scalar r/w: bank = (4*((m^(h&7))&7) + k) % 32 -> exactly 2 lanes/bank (free).
//
// Measured: 91.4 us = 5.87 TB/s effective = 93% of the 6.29 TB/s copy ceiling.
// R7 (shuffle-based, zero-LDS) regressed to 95.3 us: __shfl_xor = ds_bpermute,
// 384 DS ops/row > this version's ~160 -> do NOT replace the LDS transpose.

constexpr int DIMV = 4096;

typedef float f32x4 __attribute__((ext_vector_type(4)));  // native vec for NT builtins

__device__ __forceinline__ void bf(float& a, float& b) {
    float t = a + b;
    b = a - b;
    a = t;
}
__device__ __forceinline__ void bf4(f32x4& a, f32x4& b) {
    f32x4 t = a + b;
    b = a - b;
    a = t;
}
// FWHT on bits {0,1} (the 4 elements of one float4) — explicit temps, since
// ext_vector elements can't bind to float&.
__device__ __forceinline__ void fwht4_inner(f32x4& v) {
    float a = v.x, b = v.y, c = v.z, d = v.w;
    float t0 = a + b, t1 = a - b, t2 = c + d, t3 = c - d;
    v.x = t0 + t2;
    v.y = t1 + t3;
    v.z = t0 - t2;
    v.w = t1 - t3;
}

__global__ __launch_bounds__(64) void fwht4096_kernel(const float* __restrict__ x,
                                                      float* __restrict__ y) {
    __shared__ __align__(16) f32x4 l4[1024];
    float* lf = reinterpret_cast<float*>(l4);
    const int lane = threadIdx.x;
    const long long row = blockIdx.x;

    const f32x4* xr = reinterpret_cast<const f32x4*>(x) + row * (DIMV / 4);
    f32x4*       yr = reinterpret_cast<f32x4*>(y)       + row * (DIMV / 4);

    // ---- Load 16 float4 (non-temporal, streaming): element d = 4*lane + k + 256*q
    f32x4 v[16];
#pragma unroll
    for (int q = 0; q < 16; ++q) v[q] = __builtin_nontemporal_load(&xr[lane + 64 * q]);

    const float sc = 0.015625f;  // 1/64 = 1/sqrt(4096)
#pragma unroll
    for (int q = 0; q < 16; ++q) v[q] *= sc;

    // ---- P1a: bits 0,1 (inside each float4)
#pragma unroll
    for (int q = 0; q < 16; ++q) fwht4_inner(v[q]);

    // ---- P1b: bits 8..11 (across q)
#pragma unroll
    for (int s = 1; s < 16; s <<= 1) {
#pragma unroll
        for (int q = 0; q < 16; ++q) {
            if (!(q & s)) bf4(v[q], v[q | s]);
        }
    }

    // ---- Stage to LDS: slot s = lane + 64q, swizzled (lane ^ (q&7)) + 64q
#pragma unroll
    for (int q = 0; q < 16; ++q) l4[(lane ^ (q & 7)) + 64 * q] = v[q];

    __syncthreads();  // single-wave: pure lgkmcnt fence

    // ---- P2: lane owns (k = lane&3, h = lane>>2); d = k + 4m + 256h, m = 0..63
    {
        const int k = lane & 3;
        const int h = lane >> 2;
        const int hx = h & 7;
        const int base = 256 * h + k;   // float units
        float p[64];
#pragma unroll
        for (int m = 0; m < 64; ++m) p[m] = lf[base + 4 * (m ^ hx)];
        // fwht64 over bits 2..7
#pragma unroll
        for (int s = 1; s < 64; s <<= 1) {
#pragma unroll
            for (int i = 0; i < 64; ++i) {
                if (!(i & s)) bf(p[i], p[i | s]);
            }
        }
#pragma unroll
        for (int m = 0; m < 64; ++m) lf[base + 4 * (m ^ hx)] = p[m];
    }

    __syncthreads();  // single-wave: pure lgkmcnt fence

    // ---- Read back in load layout, coalesced non-temporal float4 stores
#pragma unroll
    for (int q = 0; q < 16; ++q) {
        f32x4 o = l4[(lane ^ (q & 7)) + 64 * q];
        __builtin_nontemporal_store(o, &yr[lane + 64 * q]);
    }
}

extern "C" void kernel_launch(void* const* d_in, const int* in_sizes, int n_in,
                              void* d_out, int out_size, void* d_ws, size_t ws_size,
                              hipStream_t stream) {
    const float* x = (const float*)d_in[0];
    float* y = (float*)d_out;
    const int rows = in_sizes[0] / DIMV;  // 16384
    dim3 grid(rows), block(64);
    hipLaunchKernelGGL(fwht4096_kernel, grid, block, 0, stream, x, y);
}